// Round 13
// baseline (443.740 us; speedup 1.0000x reference)
//
#include <hip/hip_runtime.h>
#include <math.h>

#define N_NODES 50000
#define N_EDGES 400000
#define DIM_IN  128
#define H       128
#define E_DIM   16
#define NLAYERS 3

#define K1      272        // 2H + E_DIM
#define K1P     288        // padded to multiple of 32
#define HS      136        // Hid/Mbf tile row stride (shorts, f16 k-permuted)
#define GSH     136        // gather-sum tile row stride (shorts, f16 permuted)
#define ETS     32         // e-attr tile row stride (shorts), K=32 window w/ zero pad
#define US      264        // update A-tile row stride (shorts)
#define PS      136        // proj/premul A-tile row stride (shorts)
#define AHS     136        // h' overlay row stride (shorts) inside A
#define FPS     132        // fp32 LDS row stride (floats), update epilogue
#define MB      32         // rows per tile
#define UMB     64         // rows per update block
#define UBLK    ((N_NODES + UMB - 1) / UMB)   // 782 update blocks
#define GPR     800        // gpart row length (>= UBLK)
#define NT_E    (N_EDGES / MB)   // 12500 edge tiles
#define NSB     ((N_NODES + 255) / 256)   // 196 scan blocks

typedef short    s16x8 __attribute__((ext_vector_type(8)));
typedef float    f32x4 __attribute__((ext_vector_type(4)));
typedef _Float16 f16x8 __attribute__((ext_vector_type(8)));
typedef __fp16   fp16x2 __attribute__((ext_vector_type(2)));
typedef unsigned u32x4 __attribute__((ext_vector_type(4)));

__device__ inline unsigned short f2bf(float f) {
    union { float f; unsigned u; } v; v.f = f;
    unsigned r = v.u + 0x7FFFu + ((v.u >> 16) & 1u);
    return (unsigned short)(r >> 16);
}
__device__ inline float bf2f(unsigned short u) {
    union { unsigned u; float f; } v; v.u = (unsigned)u << 16; return v.f;
}
// pack 2 f32 -> 2 f16 (RTZ) in one instruction
__device__ inline unsigned pk2(float a, float b) {
    union { fp16x2 h; unsigned u; } v;
    v.h = __builtin_amdgcn_cvt_pkrtz(a, b);
    return v.u;
}
__device__ inline float f16lo(unsigned u) {
    union { unsigned short s; _Float16 h; } v; v.s = (unsigned short)(u & 0xffffu);
    return (float)v.h;
}
__device__ inline float f16hi(unsigned u) {
    union { unsigned short s; _Float16 h; } v; v.s = (unsigned short)(u >> 16);
    return (float)v.h;
}
__device__ inline float f16s(unsigned short s) {
    union { unsigned short s; _Float16 h; } v; v.s = s;
    return (float)v.h;
}

// ---------------------------------------------------------------------------
// single fused weight convert kernel (+ hist zeroing range)
// ---------------------------------------------------------------------------
#define NW1 (NLAYERS * H * K1P)      // 110592
#define NW2 (NLAYERS * H * H)        //  49152
#define NWU (NLAYERS * H * 256)      //  98304
#define NWP (H * DIM_IN)             //  16384
#define NCONV (NW1 + NW2 + NWU + NWP + N_NODES)

__global__ __launch_bounds__(256)
void convert_all(const float* __restrict__ W1, const float* __restrict__ W2,
                 const float* __restrict__ Wu, const float* __restrict__ Wp,
                 unsigned short* __restrict__ W1t, unsigned short* __restrict__ W2t,
                 unsigned short* __restrict__ Wut, unsigned short* __restrict__ Wpt,
                 int* __restrict__ hist)
{
    int o = blockIdx.x * 256 + threadIdx.x;
    if (o < NW1) {
        // [L][272][128] f32 -> [L][128][288] bf16 (zero pad)
        const int l = o / (128 * K1P);
        const int r = o % (128 * K1P);
        const int n = r / K1P;
        const int k = r % K1P;
        const float v = (k < K1) ? W1[(size_t)l * K1 * H + (size_t)k * H + n] : 0.f;
        W1t[o] = f2bf(v);
        return;
    }
    o -= NW1;
    if (o < NW2) {
        // [L][128][128] f32 -> [L][n][P(k)] f16 (k-permuted pairs)
        const int l = o / (H * H);
        const int r = o % (H * H);
        const int n = r / H;
        const int k = r % H;
        const int kp = (k & ~31) | ((k & 15) << 1) | ((k >> 4) & 1);
        union { _Float16 h; unsigned short s; } v;
        v.h = (_Float16)W2[(size_t)l * H * H + (size_t)k * H + n];
        W2t[(size_t)l * H * H + (size_t)n * H + kp] = v.s;
        return;
    }
    o -= NW2;
    if (o < NWU) {
        // [L][256][128] -> [L][128][256] bf16
        const int l = o / (H * 256);
        const int r = o % (H * 256);
        const int n = r / 256;
        const int k = r % 256;
        Wut[o + 0] = f2bf(Wu[(size_t)l * 256 * H + (size_t)k * H + n]);
        return;
    }
    o -= NWU;
    if (o < NWP) {
        // [128][128] -> transposed bf16
        const int n = o / H;
        const int k = o % H;
        Wpt[o] = f2bf(Wp[(size_t)k * H + n]);
        return;
    }
    o -= NWP;
    if (o < N_NODES) hist[o] = 0;
}

// ---------------------------------------------------------------------------
// counting sort of edges by destination (i_idx); 3-phase parallel scan
// ---------------------------------------------------------------------------
__global__ __launch_bounds__(256)
void hist_kernel(const int* __restrict__ ei, int* __restrict__ hist)
{
    const int e = blockIdx.x * 256 + threadIdx.x;
    if (e < N_EDGES) atomicAdd(&hist[ei[e]], 1);
}

__global__ __launch_bounds__(256)
void blocksum_kernel(const int* __restrict__ hist, int* __restrict__ bsum)
{
    __shared__ int red[4];
    const int t = threadIdx.x;
    const int idx = blockIdx.x * 256 + t;
    int v = (idx < N_NODES) ? hist[idx] : 0;
#pragma unroll
    for (int off = 32; off > 0; off >>= 1) v += __shfl_xor(v, off, 64);
    if ((t & 63) == 0) red[t >> 6] = v;
    __syncthreads();
    if (t == 0) bsum[blockIdx.x] = red[0] + red[1] + red[2] + red[3];
}

__global__ __launch_bounds__(256)
void scan_bsum_kernel(const int* __restrict__ bsum, int* __restrict__ boff)
{
    __shared__ int s[256];
    const int t = threadIdx.x;
    const int v = (t < NSB) ? bsum[t] : 0;
    s[t] = v; __syncthreads();
    for (int off = 1; off < 256; off <<= 1) {
        const int u = (t >= off) ? s[t - off] : 0;
        __syncthreads();
        s[t] += u;
        __syncthreads();
    }
    if (t < NSB) boff[t] = s[t] - v;        // exclusive
}

__global__ __launch_bounds__(256)
void scan_final_kernel(const int* __restrict__ hist, const int* __restrict__ boff,
                       int* __restrict__ cursor)
{
    __shared__ int s[256];
    const int t = threadIdx.x;
    const int idx = blockIdx.x * 256 + t;
    const int v = (idx < N_NODES) ? hist[idx] : 0;
    s[t] = v; __syncthreads();
    for (int off = 1; off < 256; off <<= 1) {
        const int u = (t >= off) ? s[t - off] : 0;
        __syncthreads();
        s[t] += u;
        __syncthreads();
    }
    if (idx < N_NODES) cursor[idx] = boff[blockIdx.x] + s[t] - v;   // exclusive
}

// scatter + edge_attr conversion FUSED (R9-proven)
__global__ __launch_bounds__(256)
void scatter_kernel(const int* __restrict__ ei, int* __restrict__ cursor,
                    const float* __restrict__ ea,
                    int* __restrict__ i_s, int* __restrict__ j_s,
                    unsigned short* __restrict__ eabf)
{
    const int e = blockIdx.x * 256 + threadIdx.x;
    if (e < N_EDGES) {
        const int d = ei[e];
        const int p = atomicAdd(&cursor[d], 1);
        i_s[p] = d;
        j_s[p] = ei[N_EDGES + e];
        const float4* src = (const float4*)(ea + (size_t)e * E_DIM);
        unsigned short o[16];
#pragma unroll
        for (int q = 0; q < 4; ++q) {
            const float4 v = src[q];
            o[q * 4 + 0] = f2bf(v.x);
            o[q * 4 + 1] = f2bf(v.y);
            o[q * 4 + 2] = f2bf(v.z);
            o[q * 4 + 3] = f2bf(v.w);
        }
        uint4* dst = (uint4*)(eabf + (size_t)p * E_DIM);
        dst[0] = *(const uint4*)&o[0];
        dst[1] = *(const uint4*)&o[8];
    }
}

// ---------------------------------------------------------------------------
// proj+premul0 FUSED (R11-proven): h = bf16(x @ Wp + b) -> hbf AND LDS A;
// then Pa/Pb = f16(h @ W1[0][a|b]) permuted, in-kernel.
// ---------------------------------------------------------------------------
__global__ __launch_bounds__(256)
void proj_mfma(const float* __restrict__ x, const unsigned short* __restrict__ Wpt,
               const float* __restrict__ b, const unsigned short* __restrict__ W1t,
               unsigned short* __restrict__ hbf,
               unsigned short* __restrict__ Pa, unsigned short* __restrict__ Pb)
{
    __shared__ __align__(16) unsigned short A[MB][PS];
    const int tid = threadIdx.x;
    const int n0 = blockIdx.x * MB;
    const int wave = tid >> 6, lane = tid & 63, l15 = lane & 15, l4 = lane >> 4;
    const int colbase = wave * 32;

#pragma unroll
    for (int i = 0; i < 4; ++i) {
        const int f = tid + i * 256;
        const int row = f >> 5, c4 = f & 31;
        const int node = min(n0 + row, N_NODES - 1);
        const float4 v = *((const float4*)(x + (size_t)node * DIM_IN) + c4);
        unsigned short o[4] = { f2bf(v.x), f2bf(v.y), f2bf(v.z), f2bf(v.w) };
        *(uint2*)&A[row][c4 * 4] = *(const uint2*)o;
    }
    __syncthreads();

    f32x4 acc[2][2];
#pragma unroll
    for (int mt = 0; mt < 2; ++mt)
#pragma unroll
        for (int nt = 0; nt < 2; ++nt) acc[mt][nt] = (f32x4)0.f;

    for (int k = 0; k < DIM_IN; k += 32) {
        const s16x8 a0 = *(const s16x8*)&A[l15][k + l4 * 8];
        const s16x8 a1 = *(const s16x8*)&A[16 + l15][k + l4 * 8];
        const s16x8 b0 = *(const s16x8*)&Wpt[(size_t)(colbase + l15) * DIM_IN + k + l4 * 8];
        const s16x8 b1 = *(const s16x8*)&Wpt[(size_t)(colbase + 16 + l15) * DIM_IN + k + l4 * 8];
        acc[0][0] = __builtin_amdgcn_mfma_f32_16x16x32_bf16(a0, b0, acc[0][0], 0, 0, 0);
        acc[0][1] = __builtin_amdgcn_mfma_f32_16x16x32_bf16(a0, b1, acc[0][1], 0, 0, 0);
        acc[1][0] = __builtin_amdgcn_mfma_f32_16x16x32_bf16(a1, b0, acc[1][0], 0, 0, 0);
        acc[1][1] = __builtin_amdgcn_mfma_f32_16x16x32_bf16(a1, b1, acc[1][1], 0, 0, 0);
    }
    __syncthreads();   // all reads of x-tile in A are complete

    // h -> hbf (global) and A (LDS, overwriting x-tile)
    {
        const float bi0 = b[colbase + l15], bi1 = b[colbase + 16 + l15];
#pragma unroll
        for (int mt = 0; mt < 2; ++mt)
#pragma unroll
            for (int r = 0; r < 4; ++r) {
                const int row = mt * 16 + l4 * 4 + r;
                const int n = n0 + row;
                const unsigned short h0 = f2bf(acc[mt][0][r] + bi0);
                const unsigned short h1 = f2bf(acc[mt][1][r] + bi1);
                A[row][colbase + l15]      = h0;
                A[row][colbase + 16 + l15] = h1;
                if (n < N_NODES) {
                    hbf[(size_t)n * H + colbase + l15]      = h0;
                    hbf[(size_t)n * H + colbase + 16 + l15] = h1;
                }
            }
    }
    __syncthreads();   // h-tile ready

    // premul GEMM vs W1[0] halves a/b
    f32x4 aa[2][2], ab[2][2];
#pragma unroll
    for (int mt = 0; mt < 2; ++mt)
#pragma unroll
        for (int nt = 0; nt < 2; ++nt) { aa[mt][nt] = (f32x4)0.f; ab[mt][nt] = (f32x4)0.f; }

#pragma unroll
    for (int kt = 0; kt < 4; ++kt) {
        const s16x8 a0 = *(const s16x8*)&A[l15][kt * 32 + l4 * 8];
        const s16x8 a1 = *(const s16x8*)&A[16 + l15][kt * 32 + l4 * 8];
        const s16x8 wa0 = *(const s16x8*)&W1t[(size_t)(colbase + l15) * K1P + kt * 32 + l4 * 8];
        const s16x8 wa1 = *(const s16x8*)&W1t[(size_t)(colbase + 16 + l15) * K1P + kt * 32 + l4 * 8];
        const s16x8 wb0 = *(const s16x8*)&W1t[(size_t)(colbase + l15) * K1P + 128 + kt * 32 + l4 * 8];
        const s16x8 wb1 = *(const s16x8*)&W1t[(size_t)(colbase + 16 + l15) * K1P + 128 + kt * 32 + l4 * 8];
        aa[0][0] = __builtin_amdgcn_mfma_f32_16x16x32_bf16(a0, wa0, aa[0][0], 0, 0, 0);
        aa[0][1] = __builtin_amdgcn_mfma_f32_16x16x32_bf16(a0, wa1, aa[0][1], 0, 0, 0);
        aa[1][0] = __builtin_amdgcn_mfma_f32_16x16x32_bf16(a1, wa0, aa[1][0], 0, 0, 0);
        aa[1][1] = __builtin_amdgcn_mfma_f32_16x16x32_bf16(a1, wa1, aa[1][1], 0, 0, 0);
        ab[0][0] = __builtin_amdgcn_mfma_f32_16x16x32_bf16(a0, wb0, ab[0][0], 0, 0, 0);
        ab[0][1] = __builtin_amdgcn_mfma_f32_16x16x32_bf16(a0, wb1, ab[0][1], 0, 0, 0);
        ab[1][0] = __builtin_amdgcn_mfma_f32_16x16x32_bf16(a1, wb0, ab[1][0], 0, 0, 0);
        ab[1][1] = __builtin_amdgcn_mfma_f32_16x16x32_bf16(a1, wb1, ab[1][1], 0, 0, 0);
    }

#pragma unroll
    for (int mt = 0; mt < 2; ++mt)
#pragma unroll
        for (int r = 0; r < 4; ++r) {
            const int row = mt * 16 + l4 * 4 + r;
            const int n = n0 + row;
            if (n < N_NODES) {
                *(unsigned*)&Pa[(size_t)n * H + colbase + 2 * l15] = pk2(aa[mt][0][r], aa[mt][1][r]);
                *(unsigned*)&Pb[(size_t)n * H + colbase + 2 * l15] = pk2(ab[mt][0][r], ab[mt][1][r]);
            }
        }
}

// ---------------------------------------------------------------------------
// edge kernel (R7 structure) + XCD-chunked block swizzle: edges are sorted by
// dest, so consecutive tiles share agg lines; chunked swizzle keeps each
// XCD's 128-tile run (and its ~260KB of agg dest rows) local to one L2
// instead of ping-ponging boundary atomics across non-coherent XCD L2s.
// Grid 1024 (=8*128), 4 blocks/CU, 2-deep pipeline (proven regime).
// ---------------------------------------------------------------------------
__global__ __launch_bounds__(256, 4)
void edge_kernel(const unsigned short* __restrict__ Pa,   // [N][128] f16 permuted
                 const unsigned short* __restrict__ Pb,
                 const unsigned short* __restrict__ eabf,  // [E][16] bf16, sorted
                 const int*   __restrict__ i_s,
                 const int*   __restrict__ j_s,
                 const unsigned short* __restrict__ W1t,   // bf16 [128][288] (W1c at 256..287)
                 const float* __restrict__ b1,
                 const unsigned short* __restrict__ W2t,   // f16 [128][128] k-permuted
                 const float* __restrict__ b2,
                 float*       __restrict__ agg)
{
    __shared__ __align__(16) unsigned short Gs[MB * GSH];   // 8704 B f16 sums
    __shared__ __align__(16) unsigned short Et[MB * ETS];   // 2048 B
    __shared__ __align__(16) unsigned short Hid[MB * HS];   // 8704 B f16 permuted
    __shared__ __align__(16) unsigned short Mbf[MB * HS];   // 8704 B f16 permuted
    __shared__ int idxbuf[2][MB];                           //  256 B

    const int tid  = threadIdx.x;
    const int wave = tid >> 6;
    const int lane = tid & 63;
    const int l15  = lane & 15;
    const int l4   = lane >> 4;
    const int colbase = wave * 32;

    const int sl_e = tid >> 4;          // edge row for slot i: sl_e + i*16
    const int sl_c = tid & 15;          // uint4 chunk within row

    // weights in registers: W2 f16 frags (32 VGPR) + W1c bf16 frags (8 VGPR)
    f16x8 w2f[2][4];
    s16x8 w1cf[2];
#pragma unroll
    for (int kt = 0; kt < 4; ++kt) {
        w2f[0][kt] = *(const f16x8*)&W2t[(size_t)(colbase + l15) * H + kt * 32 + l4 * 8];
        w2f[1][kt] = *(const f16x8*)&W2t[(size_t)(colbase + 16 + l15) * H + kt * 32 + l4 * 8];
    }
    w1cf[0] = *(const s16x8*)&W1t[(size_t)(colbase + l15) * K1P + 256 + l4 * 8];
    w1cf[1] = *(const s16x8*)&W1t[(size_t)(colbase + 16 + l15) * K1P + 256 + l4 * 8];
    const float b1c0 = b1[colbase + l15], b1c1 = b1[colbase + 16 + l15];
    const float b2c0 = b2[colbase + l15], b2c1 = b2[colbase + 16 + l15];

    // reduce-phase mapping (baseline granularity): thread = 1 column,
    // half = 16-row chunk. kpc = permuted short offset of column c.
    const int rc   = tid & 127;
    const int rh   = tid >> 7;
    const int kpc  = (rc & ~31) | ((rc & 15) << 1) | ((rc >> 4) & 1);
    const int rr0  = rh * 16;

    // XCD-chunked swizzle: blocks on XCD x (bid&7==x) take tiles
    // [x*128, (x+1)*128) in each grid-stride round. Bijective (1024%8==0).
    int t = ((blockIdx.x & 7) << 7) + (blockIdx.x >> 3);
    if (t >= NT_E) return;

    // ---- prologue: stage tile t
    {
#pragma unroll
        for (int i = 0; i < 2; ++i) {
            const int e  = sl_e + i * 16;
            const int ni = i_s[t * MB + e];
            const int nj = j_s[t * MB + e];
            union { uint4 u; f16x8 h; } a, b, s;
            a.u = *((const uint4*)(Pa + (size_t)ni * H) + sl_c);
            b.u = *((const uint4*)(Pb + (size_t)nj * H) + sl_c);
            s.h = a.h + b.h;                       // 4x v_pk_add_f16
            *(uint4*)&Gs[e * GSH + sl_c * 8] = s.u;
        }
        if (tid < 64) {
            const u32x4 ve = __builtin_nontemporal_load((const u32x4*)eabf + (size_t)t * 64 + tid);
            *(u32x4*)&Et[(tid >> 1) * ETS + (tid & 1) * 8] = ve;
        } else if (tid < 128) {
            const int tt = tid - 64;
            const uint4 z = {0, 0, 0, 0};
            *(uint4*)&Et[(tt >> 1) * ETS + 16 + (tt & 1) * 8] = z;   // pad stays zero
        }
        if (tid < MB) idxbuf[0][tid] = i_s[t * MB + tid];
    }
    __syncthreads();

    int p = 0;
    for (; t < NT_E; t += gridDim.x, p ^= 1) {
        const int t1 = t + gridDim.x;

        // ---- 1. prefetch next tile into registers (raw, no conversion)
        uint4 pfa[2], pfb[2];
        u32x4 pfe = {0, 0, 0, 0};
        int   pfi = 0;
        if (t1 < NT_E) {
#pragma unroll
            for (int i = 0; i < 2; ++i) {
                const int e = sl_e + i * 16;
                pfa[i] = *((const uint4*)(Pa + (size_t)i_s[t1 * MB + e] * H) + sl_c);
                pfb[i] = *((const uint4*)(Pb + (size_t)j_s[t1 * MB + e] * H) + sl_c);
            }
            if (tid < 64) pfe = __builtin_nontemporal_load((const u32x4*)eabf + (size_t)t1 * 64 + tid);
            if (tid < MB) pfi = i_s[t1 * MB + tid];
        }

        // ---- 2. e-term MFMA (bf16, K=32 w/ zero pad); b1 folded into acc init
        f32x4 acc[2][2];
#pragma unroll
        for (int mt = 0; mt < 2; ++mt) {
            acc[mt][0] = (f32x4)(b1c0);
            acc[mt][1] = (f32x4)(b1c1);
        }
        {
            const s16x8 a0 = *(const s16x8*)&Et[l15 * ETS + l4 * 8];
            const s16x8 a1 = *(const s16x8*)&Et[(16 + l15) * ETS + l4 * 8];
            acc[0][0] = __builtin_amdgcn_mfma_f32_16x16x32_bf16(a0, w1cf[0], acc[0][0], 0, 0, 0);
            acc[0][1] = __builtin_amdgcn_mfma_f32_16x16x32_bf16(a0, w1cf[1], acc[0][1], 0, 0, 0);
            acc[1][0] = __builtin_amdgcn_mfma_f32_16x16x32_bf16(a1, w1cf[0], acc[1][0], 0, 0, 0);
            acc[1][1] = __builtin_amdgcn_mfma_f32_16x16x32_bf16(a1, w1cf[1], acc[1][1], 0, 0, 0);
        }

        // ---- 3. hid = relu(eterm + Gs + b1) -> Hid (f16 pairs, k-permuted)
#pragma unroll
        for (int mt = 0; mt < 2; ++mt)
#pragma unroll
            for (int r = 0; r < 4; ++r) {
                const int row = mt * 16 + l4 * 4 + r;
                const unsigned gv = *(const unsigned*)&Gs[row * GSH + colbase + 2 * l15];
                const unsigned hh = pk2(fmaxf(acc[mt][0][r] + f16lo(gv), 0.f),
                                        fmaxf(acc[mt][1][r] + f16hi(gv), 0.f));
                *(unsigned*)&Hid[row * HS + colbase + 2 * l15] = hh;
            }
        __syncthreads();             // barrier A: Gs/Et reads done, Hid ready

        // ---- 4. drain prefetch: pk_add -> Gs; Et; idxbuf[p^1]
        if (t1 < NT_E) {
#pragma unroll
            for (int i = 0; i < 2; ++i) {
                const int e = sl_e + i * 16;
                union { uint4 u; f16x8 h; } a, b, s;
                a.u = pfa[i]; b.u = pfb[i];
                s.h = a.h + b.h;
                *(uint4*)&Gs[e * GSH + sl_c * 8] = s.u;
            }
            if (tid < 64)
                *(u32x4*)&Et[(tid >> 1) * ETS + (tid & 1) * 8] = pfe;
            if (tid < MB) idxbuf[p ^ 1][tid] = pfi;
        }

        // ---- 5. GEMM2: Hid[32x128] x W2 (f16 MFMA, k-permuted both sides);
        //         b2 folded into acc init
#pragma unroll
        for (int mt = 0; mt < 2; ++mt) {
            acc[mt][0] = (f32x4)(b2c0);
            acc[mt][1] = (f32x4)(b2c1);
        }
#pragma unroll
        for (int kt = 0; kt < 4; ++kt) {
            const f16x8 a0 = *(const f16x8*)&Hid[l15 * HS + kt * 32 + l4 * 8];
            const f16x8 a1 = *(const f16x8*)&Hid[(16 + l15) * HS + kt * 32 + l4 * 8];
            acc[0][0] = __builtin_amdgcn_mfma_f32_16x16x32_f16(a0, w2f[0][kt], acc[0][0], 0, 0, 0);
            acc[0][1] = __builtin_amdgcn_mfma_f32_16x16x32_f16(a0, w2f[1][kt], acc[0][1], 0, 0, 0);
            acc[1][0] = __builtin_amdgcn_mfma_f32_16x16x32_f16(a1, w2f[0][kt], acc[1][0], 0, 0, 0);
            acc[1][1] = __builtin_amdgcn_mfma_f32_16x16x32_f16(a1, w2f[1][kt], acc[1][1], 0, 0, 0);
        }

        // ---- 6. m = relu(acc) -> Mbf (f16 pairs, same slot layout as Hid)
#pragma unroll
        for (int mt = 0; mt < 2; ++mt)
#pragma unroll
            for (int r = 0; r < 4; ++r) {
                const int row = mt * 16 + l4 * 4 + r;
                const unsigned mm = pk2(fmaxf(acc[mt][0][r], 0.f),
                                        fmaxf(acc[mt][1][r], 0.f));
                *(unsigned*)&Mbf[row * HS + colbase + 2 * l15] = mm;
            }
        __syncthreads();             // barrier B: Mbf ready, next tile staged

        // ---- 7. segment reduce: 2 halves x 16 rows, thread = 1 column.
        {
            const int* idxp = idxbuf[p];
            int cur = idxp[rr0];
            bool bnd = true;               // current run may extend before chunk
            float s = 0.f;
            for (int r = rr0; r < rr0 + 16; ++r) {
                const int d = idxp[r];
                if (d != cur) {
                    float* addr = &agg[(size_t)cur * H + rc];
                    if (bnd) atomicAdd(addr, s); else *addr = s;
                    s = 0.f; cur = d; bnd = false;
                }
                s += f16s(Mbf[r * HS + kpc]);
            }
            atomicAdd(&agg[(size_t)cur * H + rc], s);   // last run: may extend
        }
        // reduce(k) reads Mbf/idxbuf[p]; next writers gated by barrier A(k+1).
    }
}

// ---------------------------------------------------------------------------
// node update (MFMA, 64 rows/block): out = relu([h,agg]Wu+b); h' = LN(out+h).
// LDS = A only (33.8KB + 512B scratch) -> 4 blocks/CU. h for the LN epilogue
// is grabbed into registers from A after the MFMA barrier; h' for the fused
// premul is written into a [64][136] overlay of A after the Afp-read barrier.
// agg re-zero uses nontemporal stores (zeros don't need L2 residency).
// mode 0: re-zero agg; write hbf; FUSED premul of next layer from h' overlay.
// mode 1: no rezero, no hbf write; FUSED final LN2 + column partial sums.
// ---------------------------------------------------------------------------
__global__ __launch_bounds__(256, 4)
void update_mfma(unsigned short* __restrict__ hbf, float* __restrict__ agg,
                 const unsigned short* __restrict__ Wut, const float* __restrict__ b,
                 const float* __restrict__ g, const float* __restrict__ bln,
                 const unsigned short* __restrict__ W1n,
                 unsigned short* __restrict__ Pa, unsigned short* __restrict__ Pb,
                 const float* __restrict__ og, const float* __restrict__ ob,
                 float* __restrict__ gpart,
                 const int mode)
{
    __shared__ __align__(16) unsigned short A[UMB][US];   // 33792 B
    __shared__ float csum[128];                           //   512 B
    float* Afp = (float*)&A[0][0];                        // [64][FPS] overlay
    unsigned short* A16 = &A[0][0];                       // h' overlay [64][AHS]

    const int tid = threadIdx.x;
    const int n0 = blockIdx.x * UMB;
    const int wave = tid >> 6, lane = tid & 63, l15 = lane & 15, l4 = lane >> 4;
    const int colbase = wave * 32;

    s16x8 bf0[8], bf1[8];
#pragma unroll
    for (int kt = 0; kt < 8; ++kt) {
        bf0[kt] = *(const s16x8*)&Wut[(size_t)(colbase + l15) * 256 + kt * 32 + l4 * 8];
        bf1[kt] = *(const s16x8*)&Wut[(size_t)(colbase + 16 + l15) * 256 + kt * 32 + l4 * 8];
    }

#pragma unroll
    for (int i = 0; i < 4; ++i) {
        const int f = tid + i * 256;
        const int row = f >> 4, c = f & 15;
        const int node = min(n0 + row, N_NODES - 1);
        const uint4 v = *((const uint4*)(hbf + (size_t)node * H) + c);
        *(uint4*)&A[row][c * 8] = v;
    }
#pragma unroll
    for (int i = 0; i < 8; ++i) {
        const int f = tid + i * 256;
        const int row = f >> 5, c4 = f & 31;
        const int node = min(n0 + row, N_NODES - 1);
        float4* ap = (float4*)(agg + (size_t)node * H) + c4;
        const float4 v = *ap;
        if (mode == 0 && n0 + row < N_NODES) {
            const f32x4 z = (f32x4)0.f;
            __builtin_nontemporal_store(z, (f32x4*)ap);
        }
        unsigned short o[4] = { f2bf(v.x), f2bf(v.y), f2bf(v.z), f2bf(v.w) };
        *(uint2*)&A[row][128 + c4 * 4] = *(const uint2*)o;
    }
    __syncthreads();

    f32x4 acc[4][2];
#pragma unroll
    for (int mt = 0; mt < 4; ++mt) { acc[mt][0] = (f32x4)0.f; acc[mt][1] = (f32x4)0.f; }

#pragma unroll
    for (int kt = 0; kt < 8; ++kt) {
#pragma unroll
        for (int mt = 0; mt < 4; ++mt) {
            const s16x8 a = *(const s16x8*)&A[mt * 16 + l15][kt * 32 + l4 * 8];
            acc[mt][0] = __builtin_amdgcn_mfma_f32_16x16x32_bf16(a, bf0[kt], acc[mt][0], 0, 0, 0);
            acc[mt][1] = __builtin_amdgcn_mfma_f32_16x16x32_bf16(a, bf1[kt], acc[mt][1], 0, 0, 0);
        }
    }
    __syncthreads();

    // ---- h-save: grab this thread's LN chunk of h from A before Afp overwrite
    const int rrow = tid >> 2;
    const int rq   = tid & 3;
    const int c0   = rq * 32;
    uint4 hreg[4];
#pragma unroll
    for (int i = 0; i < 4; ++i)
        hreg[i] = *(const uint4*)&A[rrow][c0 + i * 8];
    __syncthreads();

    {
        const float bi0 = b[colbase + l15], bi1 = b[colbase + 16 + l15];
#pragma unroll
        for (int mt = 0; mt < 4; ++mt)
#pragma unroll
            for (int r = 0; r < 4; ++r) {
                const int row = mt * 16 + l4 * 4 + r;
                Afp[row * FPS + colbase + l15]      = fmaxf(acc[mt][0][r] + bi0, 0.f);
                Afp[row * FPS + colbase + 16 + l15] = fmaxf(acc[mt][1][r] + bi1, 0.f);
            }
    }
    __syncthreads();

    // ---- LN: 4 threads/row, each owns 32 cols in registers; two-pass var.
    const int nn = n0 + rrow;
    const bool valid = (nn < N_NODES);
    float v[32];
    if (valid) {
        const unsigned short* hp = (const unsigned short*)hreg;
#pragma unroll
        for (int i = 0; i < 8; ++i) {
            const float4 a = *(const float4*)&Afp[rrow * FPS + c0 + i * 4];
            v[i * 4 + 0] = a.x + bf2f(hp[i * 4 + 0]);
            v[i * 4 + 1] = a.y + bf2f(hp[i * 4 + 1]);
            v[i * 4 + 2] = a.z + bf2f(hp[i * 4 + 2]);
            v[i * 4 + 3] = a.w + bf2f(hp[i * 4 + 3]);
        }
    }
    __syncthreads();   // all Afp reads complete (h' overlay may now alias)

    if (mode == 0) {
        if (valid) {
            float s = 0.f;
#pragma unroll
            for (int i = 0; i < 32; ++i) s += v[i];
            s += __shfl_xor(s, 1, 64);
            s += __shfl_xor(s, 2, 64);
            const float mu = s * (1.f / 128.f);
            float vs = 0.f;
#pragma unroll
            for (int i = 0; i < 32; ++i) { const float d = v[i] - mu; vs += d * d; }
            vs += __shfl_xor(vs, 1, 64);
            vs += __shfl_xor(vs, 2, 64);
            const float inv = rsqrtf(vs * (1.f / 128.f) + 1e-5f);
#pragma unroll
            for (int i = 0; i < 8; ++i) {
                const float4 gv = *(const float4*)&g[c0 + i * 4];
                const float4 bv = *(const float4*)&bln[c0 + i * 4];
                unsigned short o[4] = {
                    f2bf((v[i * 4 + 0] - mu) * inv * gv.x + bv.x),
                    f2bf((v[i * 4 + 1] - mu) * inv * gv.y + bv.y),
                    f2bf((v[i * 4 + 2] - mu) * inv * gv.z + bv.z),
                    f2bf((v[i * 4 + 3] - mu) * inv * gv.w + bv.w)
                };
                *(uint2*)&hbf[(size_t)nn * H + c0 + i * 4] = *(const uint2*)o;
                *(uint2*)&A16[rrow * AHS + c0 + i * 4] = *(const uint2*)o;
            }
        }
        __syncthreads();   // h' overlay ready

        // ---- fused premul of NEXT layer: Pa/Pb = f16(h' @ W1n[a|b]) permuted
        {
            s16x8 wf0[4], wf1[4];
#pragma unroll
            for (int kt = 0; kt < 4; ++kt) {
                wf0[kt] = *(const s16x8*)&W1n[(size_t)(colbase + l15) * K1P + kt * 32 + l4 * 8];
                wf1[kt] = *(const s16x8*)&W1n[(size_t)(colbase + 16 + l15) * K1P + kt * 32 + l4 * 8];
            }
            f32x4 pacc[4][2];
#pragma unroll
            for (int mt = 0; mt < 4; ++mt) { pacc[mt][0] = (f32x4)0.f; pacc[mt][1] = (f32x4)0.f; }
#pragma unroll
            for (int kt = 0; kt < 4; ++kt)
#pragma unroll
                for (int mt = 0; mt < 4; ++mt) {
                    const s16x8 a = *(const s16x8*)&A16[(mt * 16 + l15) * AHS + kt * 32 + l4 * 8];
                    pacc[mt][0] = __builtin_amdgcn_mfma_f32_16x16x32_bf16(a, wf0[kt], pacc[mt][0], 0, 0, 0);
                    pacc[mt][1] = __builtin_amdgcn_mfma_f32_16x16x32_bf16(a, wf1[kt], pacc[mt][1], 0, 0, 0);
                }
#pragma unroll
            for (int mt = 0; mt < 4; ++mt)
#pragma unroll
                for (int r = 0; r < 4; ++r) {
                    const int row = mt * 16 + l4 * 4 + r;
                    const int n = n0 + row;
                    if (n < N_NODES)
                        *(unsigned*)&Pa[(size_t)n * H + colbase + 2 * l15] = pk2(pacc[mt][0][r], pacc[mt][1][r]);
                }
        }
        {
            s16x8 wf0[4], wf1[4];
#pragma unroll
            for (int kt = 0; kt < 4; ++kt) {
                wf0[kt] = *(const s16x8*)&W1n[(size_t)(colbase + l15) * K1P + 128 + kt * 32 + l4 * 8];
                wf1[kt] = *(const s16x8*)&W1n[(size_t)(colbase + 16 + l15) * K1P + 128 + kt * 32 + l4 * 8];
            }
            f32x4 pacc[4][2];
#pragma unroll
            for (int mt = 0; mt < 4; ++mt) { pacc[mt][0] = (f32x4)0.f; pacc[mt][1] = (f32x4)0.f; }
#pragma unroll
            for (int kt = 0; kt < 4; ++kt)
#pragma unroll
                for (int mt = 0; mt < 4; ++mt) {
                    const s16x8 a = *(const s16x8*)&A16[(mt * 16 + l15) * AHS + kt * 32 + l4 * 8];
                    pacc[mt][0] = __builtin_amdgcn_mfma_f32_16x16x32_bf16(a, wf0[kt], pacc[mt][0], 0, 0, 0);
                    pacc[mt][1] = __builtin_amdgcn_mfma_f32_16x16x32_bf16(a, wf1[kt], pacc[mt][1], 0, 0, 0);
                }
#pragma unroll
            for (int mt = 0; mt < 4; ++mt)
#pragma unroll
                for (int r = 0; r < 4; ++r) {
                    const int row = mt * 16 + l4 * 4 + r;
                    const int n = n0 + row;
                    if (n < N_NODES)
                        *(unsigned*)&Pb[(size_t)n * H + colbase + 2 * l15] = pk2(pacc[mt][0][r], pacc[mt][1][r]);
                }
        }
    } else {
        if (valid) {
            float s = 0.f;
#pragma unroll
            for (int i = 0; i < 32; ++i) s += v[i];
            s += __shfl_xor(s, 1, 64);
            s += __shfl_xor(s, 2, 64);
            const float mu = s * (1.f / 128.f);
            float vs = 0.f;
#pragma unroll
            for (int i = 0; i < 32; ++i) { const float d = v[i] - mu; vs += d * d; }
            vs += __shfl_xor(vs, 1, 64);
            vs += __shfl_xor(vs, 2, 64);
            const float inv = rsqrtf(vs * (1.f / 128.f) + 1e-5f);
            // ln1 in f32, then LN2(out_g,out_b); stash ln2 in Afp (own slots)
            float h1[32];
            float s2 = 0.f;
#pragma unroll
            for (int i = 0; i < 8; ++i) {
                const float4 gv = *(const float4*)&g[c0 + i * 4];
                const float4 bv = *(const float4*)&bln[c0 + i * 4];
                h1[i * 4 + 0] = (v[i * 4 + 0] - mu) * inv * gv.x + bv.x;
                h1[i * 4 + 1] = (v[i * 4 + 1] - mu) * inv * gv.y + bv.y;
                h1[i * 4 + 2] = (v[i * 4 + 2] - mu) * inv * gv.z + bv.z;
                h1[i * 4 + 3] = (v[i * 4 + 3] - mu) * inv * gv.w + bv.w;
                s2 += h1[i * 4 + 0] + h1[i * 4 + 1] + h1[i * 4 + 2] + h1[i * 4 + 3];
            }
            s2 += __shfl_xor(s2, 1, 64);
            s2 += __shfl_xor(s2, 2, 64);
            const float mu2 = s2 * (1.f / 128.f);
            float vs2 = 0.f;
#pragma unroll
            for (int i = 0; i < 32; ++i) { const float d = h1[i] - mu2; vs2 += d * d; }
            vs2 += __shfl_xor(vs2, 1, 64);
            vs2 += __shfl_xor(vs2, 2, 64);
            const float inv2 = rsqrtf(vs2 * (1.f / 128.f) + 1e-5f);
#pragma unroll
            for (int i = 0; i < 8; ++i) {
                const float4 gv = *(const float4*)&og[c0 + i * 4];
                const float4 bv = *(const float4*)&ob[c0 + i * 4];
                float4 o;
                o.x = (h1[i * 4 + 0] - mu2) * inv2 * gv.x + bv.x;
                o.y = (h1[i * 4 + 1] - mu2) * inv2 * gv.y + bv.y;
                o.z = (h1[i * 4 + 2] - mu2) * inv2 * gv.z + bv.z;
                o.w = (h1[i * 4 + 3] - mu2) * inv2 * gv.w + bv.w;
                *(float4*)&Afp[rrow * FPS + c0 + i * 4] = o;
            }
        } else {
            const float4 z = {0.f, 0.f, 0.f, 0.f};
#pragma unroll
            for (int i = 0; i < 8; ++i)
                *(float4*)&Afp[rrow * FPS + c0 + i * 4] = z;
        }
        __syncthreads();

        // ---- column partial sums of ln2 over the block's 64 rows
        const int col  = tid & 127;
        const int half = tid >> 7;
        float s = 0.f;
        for (int r = half * 32; r < half * 32 + 32; ++r)
            s += Afp[r * FPS + col];
        if (half) csum[col] = s;
        __syncthreads();
        if (!half)
            gpart[(size_t)col * GPR + blockIdx.x] = s + csum[col];
    }
}

// ---------------------------------------------------------------------------
// final_reduce: out[c] = sum_b gpart[c][b] / N  (128 blocks, one per column)
// ---------------------------------------------------------------------------
__global__ __launch_bounds__(256)
void final_reduce(const float* __restrict__ gpart, float* __restrict__ out)
{
    __shared__ float red[4];
    const int c = blockIdx.x;
    const int t = threadIdx.x;
    const int wave = t >> 6, lane = t & 63;
    float s = 0.f;
    for (int r = t; r < UBLK; r += 256) s += gpart[(size_t)c * GPR + r];
#pragma unroll
    for (int off = 32; off > 0; off >>= 1) s += __shfl_xor(s, off, 64);
    if (lane == 0) red[wave] = s;
    __syncthreads();
    if (t == 0) out[c] = (red[0] + red[1] + red[2] + red[3]) * (1.f / N_NODES);
}

// ---------------------------------------------------------------------------
extern "C" void kernel_launch(void* const* d_in, const int* in_sizes, int n_in,
                              void* d_out, int out_size, void* d_ws, size_t ws_size,
                              hipStream_t stream)
{
    const float* x         = (const float*)d_in[0];
    const float* edge_attr = (const float*)d_in[1];
    const int*   edge_idx  = (const int*)  d_in[2];
    const float* proj_W    = (const float*)d_in[3];
    const float* proj_b    = (const float*)d_in[4];
    const float* msg_W1    = (const float*)d_in[5];
    const float* msg_b1    = (const float*)d_in[6];
    const float* msg_W2    = (const float*)d_in[7];
    const float* msg_b2    = (const float*)d_in[8];
    const float* upd_W     = (const float*)d_in[9];
    const float* upd_b     = (const float*)d_in[10];
    const float* ln_g      = (const float*)d_in[11];
    const float* ln_b      = (const float*)d_in[12];
    const float* out_g     = (const float*)d_in[13];
    const float* out_b     = (const float*)d_in[14];
    float* out = (float*)d_out;

    char* w = (char*)d_ws;
    float* agg = (float*)w;                   w += (size_t)N_NODES * H * 4;
    unsigned short* hbf  = (unsigned short*)w; w += (size_t)N_NODES * H * 2;
    unsigned short* Pa   = (unsigned short*)w; w += (size_t)N_NODES * H * 2;
    unsigned short* Pb   = (unsigned short*)w; w += (size_t)N_NODES * H * 2;
    unsigned short* eabf = (unsigned short*)w; w += (size_t)N_EDGES * E_DIM * 2;
    unsigned short* W1t  = (unsigned short*)w; w += (size_t)NLAYERS * H * K1P * 2;
    unsigned short* W2t  = (unsigned short*)w; w += (size_t)NLAYERS * H * H * 2;
    unsigned short* Wut  = (unsigned short*)w; w += (size_t)NLAYERS * H * 256 * 2;
    unsigned short* Wpt  = (unsigned short*)w; w += (size_t)H * DIM_IN * 2;
    float* gpart = (float*)w;                 w += (size_t)H * GPR * 4;
    int* hist   = (int*)w;                    w += (size_t)N_NODES * 4;
    int* cursor = (int*)w;                    w += (size_t)N_NODES * 4;
    int* bsum   = (int*)w;                    w += (size_t)256 * 4;
    int* boff   = (int*)w;                    w += (size_t)256 * 4;
    int* i_s    = (int*)w;                    w += (size_t)N_EDGES * 4;
    int* j_s    = (int*)w;                    w += (size_t)N_EDGES * 4;

    convert_all<<<(NCONV + 255) / 256, 256, 0, stream>>>(
        msg_W1, msg_W2, upd_W, proj_W, W1t, W2t, Wut, Wpt, hist);

    hipMemsetAsync(agg, 0, (size_t)N_NODES * H * sizeof(float), stream);  // once; update re-zeroes
    hist_kernel<<<(N_EDGES + 255) / 256, 256, 0, stream>>>(edge_idx, hist);
    blocksum_kernel<<<NSB, 256, 0, stream>>>(hist, bsum);
    scan_bsum_kernel<<<1, 256, 0, stream>>>(bsum, boff);
    scan_final_kernel<<<NSB, 256, 0, stream>>>(hist, boff, cursor);
    scatter_kernel<<<(N_EDGES + 255) / 256, 256, 0, stream>>>(edge_idx, cursor, edge_attr, i_s, j_s, eabf);

    const int nblk = (N_NODES + MB - 1) / MB;
    proj_mfma<<<nblk, 256, 0, stream>>>(x, Wpt, proj_b, W1t, hbf, Pa, Pb);

    for (int l = 0; l < NLAYERS; ++l) {
        edge_kernel<<<1024, 256, 0, stream>>>(
            Pa, Pb, eabf, i_s, j_s,
            W1t + (size_t)l * H * K1P, msg_b1 + (size_t)l * H,
            W2t + (size_t)l * H * H,   msg_b2 + (size_t)l * H, agg);
        update_mfma<<<UBLK, 256, 0, stream>>>(
            hbf, agg, Wut + (size_t)l * H * 256, upd_b + (size_t)l * H,
            ln_g + (size_t)l * H, ln_b + (size_t)l * H,
            W1t + (size_t)((l < NLAYERS - 1) ? (l + 1) : 0) * H * K1P,
            Pa, Pb, out_g, out_b, gpart,
            (l < NLAYERS - 1) ? 0 : 1);
    }

    final_reduce<<<H, 256, 0, stream>>>(gpart, out);
}

// Round 14
// 434.371 us; speedup vs baseline: 1.0216x; 1.0216x over previous
//
#include <hip/hip_runtime.h>
#include <math.h>

#define N_NODES 50000
#define N_EDGES 400000
#define DIM_IN  128
#define H       128
#define E_DIM   16
#define NLAYERS 3

#define K1      272        // 2H + E_DIM
#define K1P     288        // padded to multiple of 32
#define HS      136        // Hid/Mbf tile row stride (shorts, f16 k-permuted)
#define GSH     136        // gather-sum tile row stride (shorts, f16 permuted)
#define ETS     32         // e-attr tile row stride (shorts), K=32 window w/ zero pad
#define US      264        // update A-tile row stride (shorts)
#define PS      136        // proj/premul A-tile row stride (shorts)
#define AHS     136        // h' overlay row stride (shorts) inside A
#define FPS     132        // fp32 LDS row stride (floats), update epilogue
#define MB      32         // rows per tile
#define UMB     64         // rows per update block
#define UBLK    ((N_NODES + UMB - 1) / UMB)   // 782 update blocks
#define GPR     800        // gpart row length (>= UBLK)
#define NT_E    (N_EDGES / MB)   // 12500 edge tiles
#define NSB     ((N_NODES + 255) / 256)   // 196 scan blocks

typedef short    s16x8 __attribute__((ext_vector_type(8)));
typedef float    f32x4 __attribute__((ext_vector_type(4)));
typedef _Float16 f16x8 __attribute__((ext_vector_type(8)));
typedef __fp16   fp16x2 __attribute__((ext_vector_type(2)));
typedef unsigned u32x4 __attribute__((ext_vector_type(4)));

__device__ inline unsigned short f2bf(float f) {
    union { float f; unsigned u; } v; v.f = f;
    unsigned r = v.u + 0x7FFFu + ((v.u >> 16) & 1u);
    return (unsigned short)(r >> 16);
}
__device__ inline float bf2f(unsigned short u) {
    union { unsigned u; float f; } v; v.u = (unsigned)u << 16; return v.f;
}
// pack 2 f32 -> 2 f16 (RTZ) in one instruction
__device__ inline unsigned pk2(float a, float b) {
    union { fp16x2 h; unsigned u; } v;
    v.h = __builtin_amdgcn_cvt_pkrtz(a, b);
    return v.u;
}
__device__ inline float f16lo(unsigned u) {
    union { unsigned short s; _Float16 h; } v; v.s = (unsigned short)(u & 0xffffu);
    return (float)v.h;
}
__device__ inline float f16hi(unsigned u) {
    union { unsigned short s; _Float16 h; } v; v.s = (unsigned short)(u >> 16);
    return (float)v.h;
}
__device__ inline float f16s(unsigned short s) {
    union { unsigned short s; _Float16 h; } v; v.s = s;
    return (float)v.h;
}

// ---------------------------------------------------------------------------
// single fused weight convert kernel (+ hist zeroing range)
// ---------------------------------------------------------------------------
#define NW1 (NLAYERS * H * K1P)      // 110592
#define NW2 (NLAYERS * H * H)        //  49152
#define NWU (NLAYERS * H * 256)      //  98304
#define NWP (H * DIM_IN)             //  16384
#define NCONV (NW1 + NW2 + NWU + NWP + N_NODES)

__global__ __launch_bounds__(256)
void convert_all(const float* __restrict__ W1, const float* __restrict__ W2,
                 const float* __restrict__ Wu, const float* __restrict__ Wp,
                 unsigned short* __restrict__ W1t, unsigned short* __restrict__ W2t,
                 unsigned short* __restrict__ Wut, unsigned short* __restrict__ Wpt,
                 int* __restrict__ hist)
{
    int o = blockIdx.x * 256 + threadIdx.x;
    if (o < NW1) {
        // [L][272][128] f32 -> [L][128][288] bf16 (zero pad)
        const int l = o / (128 * K1P);
        const int r = o % (128 * K1P);
        const int n = r / K1P;
        const int k = r % K1P;
        const float v = (k < K1) ? W1[(size_t)l * K1 * H + (size_t)k * H + n] : 0.f;
        W1t[o] = f2bf(v);
        return;
    }
    o -= NW1;
    if (o < NW2) {
        // [L][128][128] f32 -> [L][n][P(k)] f16 (k-permuted pairs)
        const int l = o / (H * H);
        const int r = o % (H * H);
        const int n = r / H;
        const int k = r % H;
        const int kp = (k & ~31) | ((k & 15) << 1) | ((k >> 4) & 1);
        union { _Float16 h; unsigned short s; } v;
        v.h = (_Float16)W2[(size_t)l * H * H + (size_t)k * H + n];
        W2t[(size_t)l * H * H + (size_t)n * H + kp] = v.s;
        return;
    }
    o -= NW2;
    if (o < NWU) {
        // [L][256][128] -> [L][128][256] bf16
        const int l = o / (H * 256);
        const int r = o % (H * 256);
        const int n = r / 256;
        const int k = r % 256;
        Wut[o + 0] = f2bf(Wu[(size_t)l * 256 * H + (size_t)k * H + n]);
        return;
    }
    o -= NWU;
    if (o < NWP) {
        // [128][128] -> transposed bf16
        const int n = o / H;
        const int k = o % H;
        Wpt[o] = f2bf(Wp[(size_t)k * H + n]);
        return;
    }
    o -= NWP;
    if (o < N_NODES) hist[o] = 0;
}

// ---------------------------------------------------------------------------
// counting sort of edges by destination (i_idx); 3-phase parallel scan
// ---------------------------------------------------------------------------
__global__ __launch_bounds__(256)
void hist_kernel(const int* __restrict__ ei, int* __restrict__ hist)
{
    const int e = blockIdx.x * 256 + threadIdx.x;
    if (e < N_EDGES) atomicAdd(&hist[ei[e]], 1);
}

__global__ __launch_bounds__(256)
void blocksum_kernel(const int* __restrict__ hist, int* __restrict__ bsum)
{
    __shared__ int red[4];
    const int t = threadIdx.x;
    const int idx = blockIdx.x * 256 + t;
    int v = (idx < N_NODES) ? hist[idx] : 0;
#pragma unroll
    for (int off = 32; off > 0; off >>= 1) v += __shfl_xor(v, off, 64);
    if ((t & 63) == 0) red[t >> 6] = v;
    __syncthreads();
    if (t == 0) bsum[blockIdx.x] = red[0] + red[1] + red[2] + red[3];
}

__global__ __launch_bounds__(256)
void scan_bsum_kernel(const int* __restrict__ bsum, int* __restrict__ boff)
{
    __shared__ int s[256];
    const int t = threadIdx.x;
    const int v = (t < NSB) ? bsum[t] : 0;
    s[t] = v; __syncthreads();
    for (int off = 1; off < 256; off <<= 1) {
        const int u = (t >= off) ? s[t - off] : 0;
        __syncthreads();
        s[t] += u;
        __syncthreads();
    }
    if (t < NSB) boff[t] = s[t] - v;        // exclusive
}

__global__ __launch_bounds__(256)
void scan_final_kernel(const int* __restrict__ hist, const int* __restrict__ boff,
                       int* __restrict__ cursor)
{
    __shared__ int s[256];
    const int t = threadIdx.x;
    const int idx = blockIdx.x * 256 + t;
    const int v = (idx < N_NODES) ? hist[idx] : 0;
    s[t] = v; __syncthreads();
    for (int off = 1; off < 256; off <<= 1) {
        const int u = (t >= off) ? s[t - off] : 0;
        __syncthreads();
        s[t] += u;
        __syncthreads();
    }
    if (idx < N_NODES) cursor[idx] = boff[blockIdx.x] + s[t] - v;   // exclusive
}

// scatter + edge_attr conversion FUSED (R9-proven)
__global__ __launch_bounds__(256)
void scatter_kernel(const int* __restrict__ ei, int* __restrict__ cursor,
                    const float* __restrict__ ea,
                    int* __restrict__ i_s, int* __restrict__ j_s,
                    unsigned short* __restrict__ eabf)
{
    const int e = blockIdx.x * 256 + threadIdx.x;
    if (e < N_EDGES) {
        const int d = ei[e];
        const int p = atomicAdd(&cursor[d], 1);
        i_s[p] = d;
        j_s[p] = ei[N_EDGES + e];
        const float4* src = (const float4*)(ea + (size_t)e * E_DIM);
        unsigned short o[16];
#pragma unroll
        for (int q = 0; q < 4; ++q) {
            const float4 v = src[q];
            o[q * 4 + 0] = f2bf(v.x);
            o[q * 4 + 1] = f2bf(v.y);
            o[q * 4 + 2] = f2bf(v.z);
            o[q * 4 + 3] = f2bf(v.w);
        }
        uint4* dst = (uint4*)(eabf + (size_t)p * E_DIM);
        dst[0] = *(const uint4*)&o[0];
        dst[1] = *(const uint4*)&o[8];
    }
}

// ---------------------------------------------------------------------------
// proj+premul0 FUSED (R11-proven): h = bf16(x @ Wp + b) -> hbf AND LDS A;
// then Pa/Pb = f16(h @ W1[0][a|b]) permuted, in-kernel.
// ---------------------------------------------------------------------------
__global__ __launch_bounds__(256)
void proj_mfma(const float* __restrict__ x, const unsigned short* __restrict__ Wpt,
               const float* __restrict__ b, const unsigned short* __restrict__ W1t,
               unsigned short* __restrict__ hbf,
               unsigned short* __restrict__ Pa, unsigned short* __restrict__ Pb)
{
    __shared__ __align__(16) unsigned short A[MB][PS];
    const int tid = threadIdx.x;
    const int n0 = blockIdx.x * MB;
    const int wave = tid >> 6, lane = tid & 63, l15 = lane & 15, l4 = lane >> 4;
    const int colbase = wave * 32;

#pragma unroll
    for (int i = 0; i < 4; ++i) {
        const int f = tid + i * 256;
        const int row = f >> 5, c4 = f & 31;
        const int node = min(n0 + row, N_NODES - 1);
        const float4 v = *((const float4*)(x + (size_t)node * DIM_IN) + c4);
        unsigned short o[4] = { f2bf(v.x), f2bf(v.y), f2bf(v.z), f2bf(v.w) };
        *(uint2*)&A[row][c4 * 4] = *(const uint2*)o;
    }
    __syncthreads();

    f32x4 acc[2][2];
#pragma unroll
    for (int mt = 0; mt < 2; ++mt)
#pragma unroll
        for (int nt = 0; nt < 2; ++nt) acc[mt][nt] = (f32x4)0.f;

    for (int k = 0; k < DIM_IN; k += 32) {
        const s16x8 a0 = *(const s16x8*)&A[l15][k + l4 * 8];
        const s16x8 a1 = *(const s16x8*)&A[16 + l15][k + l4 * 8];
        const s16x8 b0 = *(const s16x8*)&Wpt[(size_t)(colbase + l15) * DIM_IN + k + l4 * 8];
        const s16x8 b1 = *(const s16x8*)&Wpt[(size_t)(colbase + 16 + l15) * DIM_IN + k + l4 * 8];
        acc[0][0] = __builtin_amdgcn_mfma_f32_16x16x32_bf16(a0, b0, acc[0][0], 0, 0, 0);
        acc[0][1] = __builtin_amdgcn_mfma_f32_16x16x32_bf16(a0, b1, acc[0][1], 0, 0, 0);
        acc[1][0] = __builtin_amdgcn_mfma_f32_16x16x32_bf16(a1, b0, acc[1][0], 0, 0, 0);
        acc[1][1] = __builtin_amdgcn_mfma_f32_16x16x32_bf16(a1, b1, acc[1][1], 0, 0, 0);
    }
    __syncthreads();   // all reads of x-tile in A are complete

    // h -> hbf (global) and A (LDS, overwriting x-tile)
    {
        const float bi0 = b[colbase + l15], bi1 = b[colbase + 16 + l15];
#pragma unroll
        for (int mt = 0; mt < 2; ++mt)
#pragma unroll
            for (int r = 0; r < 4; ++r) {
                const int row = mt * 16 + l4 * 4 + r;
                const int n = n0 + row;
                const unsigned short h0 = f2bf(acc[mt][0][r] + bi0);
                const unsigned short h1 = f2bf(acc[mt][1][r] + bi1);
                A[row][colbase + l15]      = h0;
                A[row][colbase + 16 + l15] = h1;
                if (n < N_NODES) {
                    hbf[(size_t)n * H + colbase + l15]      = h0;
                    hbf[(size_t)n * H + colbase + 16 + l15] = h1;
                }
            }
    }
    __syncthreads();   // h-tile ready

    // premul GEMM vs W1[0] halves a/b
    f32x4 aa[2][2], ab[2][2];
#pragma unroll
    for (int mt = 0; mt < 2; ++mt)
#pragma unroll
        for (int nt = 0; nt < 2; ++nt) { aa[mt][nt] = (f32x4)0.f; ab[mt][nt] = (f32x4)0.f; }

#pragma unroll
    for (int kt = 0; kt < 4; ++kt) {
        const s16x8 a0 = *(const s16x8*)&A[l15][kt * 32 + l4 * 8];
        const s16x8 a1 = *(const s16x8*)&A[16 + l15][kt * 32 + l4 * 8];
        const s16x8 wa0 = *(const s16x8*)&W1t[(size_t)(colbase + l15) * K1P + kt * 32 + l4 * 8];
        const s16x8 wa1 = *(const s16x8*)&W1t[(size_t)(colbase + 16 + l15) * K1P + kt * 32 + l4 * 8];
        const s16x8 wb0 = *(const s16x8*)&W1t[(size_t)(colbase + l15) * K1P + 128 + kt * 32 + l4 * 8];
        const s16x8 wb1 = *(const s16x8*)&W1t[(size_t)(colbase + 16 + l15) * K1P + 128 + kt * 32 + l4 * 8];
        aa[0][0] = __builtin_amdgcn_mfma_f32_16x16x32_bf16(a0, wa0, aa[0][0], 0, 0, 0);
        aa[0][1] = __builtin_amdgcn_mfma_f32_16x16x32_bf16(a0, wa1, aa[0][1], 0, 0, 0);
        aa[1][0] = __builtin_amdgcn_mfma_f32_16x16x32_bf16(a1, wa0, aa[1][0], 0, 0, 0);
        aa[1][1] = __builtin_amdgcn_mfma_f32_16x16x32_bf16(a1, wa1, aa[1][1], 0, 0, 0);
        ab[0][0] = __builtin_amdgcn_mfma_f32_16x16x32_bf16(a0, wb0, ab[0][0], 0, 0, 0);
        ab[0][1] = __builtin_amdgcn_mfma_f32_16x16x32_bf16(a0, wb1, ab[0][1], 0, 0, 0);
        ab[1][0] = __builtin_amdgcn_mfma_f32_16x16x32_bf16(a1, wb0, ab[1][0], 0, 0, 0);
        ab[1][1] = __builtin_amdgcn_mfma_f32_16x16x32_bf16(a1, wb1, ab[1][1], 0, 0, 0);
    }

#pragma unroll
    for (int mt = 0; mt < 2; ++mt)
#pragma unroll
        for (int r = 0; r < 4; ++r) {
            const int row = mt * 16 + l4 * 4 + r;
            const int n = n0 + row;
            if (n < N_NODES) {
                *(unsigned*)&Pa[(size_t)n * H + colbase + 2 * l15] = pk2(aa[mt][0][r], aa[mt][1][r]);
                *(unsigned*)&Pb[(size_t)n * H + colbase + 2 * l15] = pk2(ab[mt][0][r], ab[mt][1][r]);
            }
        }
}

// ---------------------------------------------------------------------------
// edge kernel (R7/R12-proven, natural tile order): f16 data path + segment
// reduce at the proven cache regime: grid 1024, 4 blocks/CU, 2-deep pipeline.
// (R13's XCD-chunked swizzle regressed: sequential tile order wins on DRAM
// page locality; agg write traffic is compulsory.)
// ---------------------------------------------------------------------------
__global__ __launch_bounds__(256, 4)
void edge_kernel(const unsigned short* __restrict__ Pa,   // [N][128] f16 permuted
                 const unsigned short* __restrict__ Pb,
                 const unsigned short* __restrict__ eabf,  // [E][16] bf16, sorted
                 const int*   __restrict__ i_s,
                 const int*   __restrict__ j_s,
                 const unsigned short* __restrict__ W1t,   // bf16 [128][288] (W1c at 256..287)
                 const float* __restrict__ b1,
                 const unsigned short* __restrict__ W2t,   // f16 [128][128] k-permuted
                 const float* __restrict__ b2,
                 float*       __restrict__ agg)
{
    __shared__ __align__(16) unsigned short Gs[MB * GSH];   // 8704 B f16 sums
    __shared__ __align__(16) unsigned short Et[MB * ETS];   // 2048 B
    __shared__ __align__(16) unsigned short Hid[MB * HS];   // 8704 B f16 permuted
    __shared__ __align__(16) unsigned short Mbf[MB * HS];   // 8704 B f16 permuted
    __shared__ int idxbuf[2][MB];                           //  256 B

    const int tid  = threadIdx.x;
    const int wave = tid >> 6;
    const int lane = tid & 63;
    const int l15  = lane & 15;
    const int l4   = lane >> 4;
    const int colbase = wave * 32;

    const int sl_e = tid >> 4;          // edge row for slot i: sl_e + i*16
    const int sl_c = tid & 15;          // uint4 chunk within row

    // weights in registers: W2 f16 frags (32 VGPR) + W1c bf16 frags (8 VGPR)
    f16x8 w2f[2][4];
    s16x8 w1cf[2];
#pragma unroll
    for (int kt = 0; kt < 4; ++kt) {
        w2f[0][kt] = *(const f16x8*)&W2t[(size_t)(colbase + l15) * H + kt * 32 + l4 * 8];
        w2f[1][kt] = *(const f16x8*)&W2t[(size_t)(colbase + 16 + l15) * H + kt * 32 + l4 * 8];
    }
    w1cf[0] = *(const s16x8*)&W1t[(size_t)(colbase + l15) * K1P + 256 + l4 * 8];
    w1cf[1] = *(const s16x8*)&W1t[(size_t)(colbase + 16 + l15) * K1P + 256 + l4 * 8];
    const float b1c0 = b1[colbase + l15], b1c1 = b1[colbase + 16 + l15];
    const float b2c0 = b2[colbase + l15], b2c1 = b2[colbase + 16 + l15];

    // reduce-phase mapping (baseline granularity): thread = 1 column,
    // half = 16-row chunk. kpc = permuted short offset of column c.
    const int rc   = tid & 127;
    const int rh   = tid >> 7;
    const int kpc  = (rc & ~31) | ((rc & 15) << 1) | ((rc >> 4) & 1);
    const int rr0  = rh * 16;

    int t = blockIdx.x;
    if (t >= NT_E) return;

    // ---- prologue: stage tile t
    {
#pragma unroll
        for (int i = 0; i < 2; ++i) {
            const int e  = sl_e + i * 16;
            const int ni = i_s[t * MB + e];
            const int nj = j_s[t * MB + e];
            union { uint4 u; f16x8 h; } a, b, s;
            a.u = *((const uint4*)(Pa + (size_t)ni * H) + sl_c);
            b.u = *((const uint4*)(Pb + (size_t)nj * H) + sl_c);
            s.h = a.h + b.h;                       // 4x v_pk_add_f16
            *(uint4*)&Gs[e * GSH + sl_c * 8] = s.u;
        }
        if (tid < 64) {
            const u32x4 ve = __builtin_nontemporal_load((const u32x4*)eabf + (size_t)t * 64 + tid);
            *(u32x4*)&Et[(tid >> 1) * ETS + (tid & 1) * 8] = ve;
        } else if (tid < 128) {
            const int tt = tid - 64;
            const uint4 z = {0, 0, 0, 0};
            *(uint4*)&Et[(tt >> 1) * ETS + 16 + (tt & 1) * 8] = z;   // pad stays zero
        }
        if (tid < MB) idxbuf[0][tid] = i_s[t * MB + tid];
    }
    __syncthreads();

    int p = 0;
    for (; t < NT_E; t += gridDim.x, p ^= 1) {
        const int t1 = t + gridDim.x;

        // ---- 1. prefetch next tile into registers (raw, no conversion)
        uint4 pfa[2], pfb[2];
        u32x4 pfe = {0, 0, 0, 0};
        int   pfi = 0;
        if (t1 < NT_E) {
#pragma unroll
            for (int i = 0; i < 2; ++i) {
                const int e = sl_e + i * 16;
                pfa[i] = *((const uint4*)(Pa + (size_t)i_s[t1 * MB + e] * H) + sl_c);
                pfb[i] = *((const uint4*)(Pb + (size_t)j_s[t1 * MB + e] * H) + sl_c);
            }
            if (tid < 64) pfe = __builtin_nontemporal_load((const u32x4*)eabf + (size_t)t1 * 64 + tid);
            if (tid < MB) pfi = i_s[t1 * MB + tid];
        }

        // ---- 2. e-term MFMA (bf16, K=32 w/ zero pad); b1 folded into acc init
        f32x4 acc[2][2];
#pragma unroll
        for (int mt = 0; mt < 2; ++mt) {
            acc[mt][0] = (f32x4)(b1c0);
            acc[mt][1] = (f32x4)(b1c1);
        }
        {
            const s16x8 a0 = *(const s16x8*)&Et[l15 * ETS + l4 * 8];
            const s16x8 a1 = *(const s16x8*)&Et[(16 + l15) * ETS + l4 * 8];
            acc[0][0] = __builtin_amdgcn_mfma_f32_16x16x32_bf16(a0, w1cf[0], acc[0][0], 0, 0, 0);
            acc[0][1] = __builtin_amdgcn_mfma_f32_16x16x32_bf16(a0, w1cf[1], acc[0][1], 0, 0, 0);
            acc[1][0] = __builtin_amdgcn_mfma_f32_16x16x32_bf16(a1, w1cf[0], acc[1][0], 0, 0, 0);
            acc[1][1] = __builtin_amdgcn_mfma_f32_16x16x32_bf16(a1, w1cf[1], acc[1][1], 0, 0, 0);
        }

        // ---- 3. hid = relu(eterm + Gs + b1) -> Hid (f16 pairs, k-permuted)
#pragma unroll
        for (int mt = 0; mt < 2; ++mt)
#pragma unroll
            for (int r = 0; r < 4; ++r) {
                const int row = mt * 16 + l4 * 4 + r;
                const unsigned gv = *(const unsigned*)&Gs[row * GSH + colbase + 2 * l15];
                const unsigned hh = pk2(fmaxf(acc[mt][0][r] + f16lo(gv), 0.f),
                                        fmaxf(acc[mt][1][r] + f16hi(gv), 0.f));
                *(unsigned*)&Hid[row * HS + colbase + 2 * l15] = hh;
            }
        __syncthreads();             // barrier A: Gs/Et reads done, Hid ready

        // ---- 4. drain prefetch: pk_add -> Gs; Et; idxbuf[p^1]
        if (t1 < NT_E) {
#pragma unroll
            for (int i = 0; i < 2; ++i) {
                const int e = sl_e + i * 16;
                union { uint4 u; f16x8 h; } a, b, s;
                a.u = pfa[i]; b.u = pfb[i];
                s.h = a.h + b.h;
                *(uint4*)&Gs[e * GSH + sl_c * 8] = s.u;
            }
            if (tid < 64)
                *(u32x4*)&Et[(tid >> 1) * ETS + (tid & 1) * 8] = pfe;
            if (tid < MB) idxbuf[p ^ 1][tid] = pfi;
        }

        // ---- 5. GEMM2: Hid[32x128] x W2 (f16 MFMA, k-permuted both sides);
        //         b2 folded into acc init
#pragma unroll
        for (int mt = 0; mt < 2; ++mt) {
            acc[mt][0] = (f32x4)(b2c0);
            acc[mt][1] = (f32x4)(b2c1);
        }
#pragma unroll
        for (int kt = 0; kt < 4; ++kt) {
            const f16x8 a0 = *(const f16x8*)&Hid[l15 * HS + kt * 32 + l4 * 8];
            const f16x8 a1 = *(const f16x8*)&Hid[(16 + l15) * HS + kt * 32 + l4 * 8];
            acc[0][0] = __builtin_amdgcn_mfma_f32_16x16x32_f16(a0, w2f[0][kt], acc[0][0], 0, 0, 0);
            acc[0][1] = __builtin_amdgcn_mfma_f32_16x16x32_f16(a0, w2f[1][kt], acc[0][1], 0, 0, 0);
            acc[1][0] = __builtin_amdgcn_mfma_f32_16x16x32_f16(a1, w2f[0][kt], acc[1][0], 0, 0, 0);
            acc[1][1] = __builtin_amdgcn_mfma_f32_16x16x32_f16(a1, w2f[1][kt], acc[1][1], 0, 0, 0);
        }

        // ---- 6. m = relu(acc) -> Mbf (f16 pairs, same slot layout as Hid)
#pragma unroll
        for (int mt = 0; mt < 2; ++mt)
#pragma unroll
            for (int r = 0; r < 4; ++r) {
                const int row = mt * 16 + l4 * 4 + r;
                const unsigned mm = pk2(fmaxf(acc[mt][0][r], 0.f),
                                        fmaxf(acc[mt][1][r], 0.f));
                *(unsigned*)&Mbf[row * HS + colbase + 2 * l15] = mm;
            }
        __syncthreads();             // barrier B: Mbf ready, next tile staged

        // ---- 7. segment reduce: 2 halves x 16 rows, thread = 1 column.
        {
            const int* idxp = idxbuf[p];
            int cur = idxp[rr0];
            bool bnd = true;               // current run may extend before chunk
            float s = 0.f;
            for (int r = rr0; r < rr0 + 16; ++r) {
                const int d = idxp[r];
                if (d != cur) {
                    float* addr = &agg[(size_t)cur * H + rc];
                    if (bnd) atomicAdd(addr, s); else *addr = s;
                    s = 0.f; cur = d; bnd = false;
                }
                s += f16s(Mbf[r * HS + kpc]);
            }
            atomicAdd(&agg[(size_t)cur * H + rc], s);   // last run: may extend
        }
        // reduce(k) reads Mbf/idxbuf[p]; next writers gated by barrier A(k+1).
    }
}

// ---------------------------------------------------------------------------
// node update (MFMA, 64 rows/block): out = relu([h,agg]Wu+b); h' = LN(out+h).
// LDS = A only (33.8KB + 512B scratch) -> 4 blocks/CU. h for the LN epilogue
// is grabbed into registers from A after the MFMA barrier; h' for the fused
// premul is written into a [64][136] overlay of A after the Afp-read barrier.
// mode 0: re-zero agg; write hbf; FUSED premul of next layer from h' overlay.
// mode 1: no rezero, no hbf write; FUSED final LN2 + column partial sums.
// ---------------------------------------------------------------------------
__global__ __launch_bounds__(256, 4)
void update_mfma(unsigned short* __restrict__ hbf, float* __restrict__ agg,
                 const unsigned short* __restrict__ Wut, const float* __restrict__ b,
                 const float* __restrict__ g, const float* __restrict__ bln,
                 const unsigned short* __restrict__ W1n,
                 unsigned short* __restrict__ Pa, unsigned short* __restrict__ Pb,
                 const float* __restrict__ og, const float* __restrict__ ob,
                 float* __restrict__ gpart,
                 const int mode)
{
    __shared__ __align__(16) unsigned short A[UMB][US];   // 33792 B
    __shared__ float csum[128];                           //   512 B
    float* Afp = (float*)&A[0][0];                        // [64][FPS] overlay
    unsigned short* A16 = &A[0][0];                       // h' overlay [64][AHS]

    const int tid = threadIdx.x;
    const int n0 = blockIdx.x * UMB;
    const int wave = tid >> 6, lane = tid & 63, l15 = lane & 15, l4 = lane >> 4;
    const int colbase = wave * 32;

    s16x8 bf0[8], bf1[8];
#pragma unroll
    for (int kt = 0; kt < 8; ++kt) {
        bf0[kt] = *(const s16x8*)&Wut[(size_t)(colbase + l15) * 256 + kt * 32 + l4 * 8];
        bf1[kt] = *(const s16x8*)&Wut[(size_t)(colbase + 16 + l15) * 256 + kt * 32 + l4 * 8];
    }

#pragma unroll
    for (int i = 0; i < 4; ++i) {
        const int f = tid + i * 256;
        const int row = f >> 4, c = f & 15;
        const int node = min(n0 + row, N_NODES - 1);
        const uint4 v = *((const uint4*)(hbf + (size_t)node * H) + c);
        *(uint4*)&A[row][c * 8] = v;
    }
#pragma unroll
    for (int i = 0; i < 8; ++i) {
        const int f = tid + i * 256;
        const int row = f >> 5, c4 = f & 31;
        const int node = min(n0 + row, N_NODES - 1);
        float4* ap = (float4*)(agg + (size_t)node * H) + c4;
        const float4 v = *ap;
        if (mode == 0 && n0 + row < N_NODES) {
            const float4 z = {0.f, 0.f, 0.f, 0.f};
            *ap = z;
        }
        unsigned short o[4] = { f2bf(v.x), f2bf(v.y), f2bf(v.z), f2bf(v.w) };
        *(uint2*)&A[row][128 + c4 * 4] = *(const uint2*)o;
    }
    __syncthreads();

    f32x4 acc[4][2];
#pragma unroll
    for (int mt = 0; mt < 4; ++mt) { acc[mt][0] = (f32x4)0.f; acc[mt][1] = (f32x4)0.f; }

#pragma unroll
    for (int kt = 0; kt < 8; ++kt) {
#pragma unroll
        for (int mt = 0; mt < 4; ++mt) {
            const s16x8 a = *(const s16x8*)&A[mt * 16 + l15][kt * 32 + l4 * 8];
            acc[mt][0] = __builtin_amdgcn_mfma_f32_16x16x32_bf16(a, bf0[kt], acc[mt][0], 0, 0, 0);
            acc[mt][1] = __builtin_amdgcn_mfma_f32_16x16x32_bf16(a, bf1[kt], acc[mt][1], 0, 0, 0);
        }
    }
    __syncthreads();

    // ---- h-save: grab this thread's LN chunk of h from A before Afp overwrite
    const int rrow = tid >> 2;
    const int rq   = tid & 3;
    const int c0   = rq * 32;
    uint4 hreg[4];
#pragma unroll
    for (int i = 0; i < 4; ++i)
        hreg[i] = *(const uint4*)&A[rrow][c0 + i * 8];
    __syncthreads();

    {
        const float bi0 = b[colbase + l15], bi1 = b[colbase + 16 + l15];
#pragma unroll
        for (int mt = 0; mt < 4; ++mt)
#pragma unroll
            for (int r = 0; r < 4; ++r) {
                const int row = mt * 16 + l4 * 4 + r;
                Afp[row * FPS + colbase + l15]      = fmaxf(acc[mt][0][r] + bi0, 0.f);
                Afp[row * FPS + colbase + 16 + l15] = fmaxf(acc[mt][1][r] + bi1, 0.f);
            }
    }
    __syncthreads();

    // ---- LN: 4 threads/row, each owns 32 cols in registers; two-pass var.
    const int nn = n0 + rrow;
    const bool valid = (nn < N_NODES);
    float v[32];
    if (valid) {
        const unsigned short* hp = (const unsigned short*)hreg;
#pragma unroll
        for (int i = 0; i < 8; ++i) {
            const float4 a = *(const float4*)&Afp[rrow * FPS + c0 + i * 4];
            v[i * 4 + 0] = a.x + bf2f(hp[i * 4 + 0]);
            v[i * 4 + 1] = a.y + bf2f(hp[i * 4 + 1]);
            v[i * 4 + 2] = a.z + bf2f(hp[i * 4 + 2]);
            v[i * 4 + 3] = a.w + bf2f(hp[i * 4 + 3]);
        }
    }
    __syncthreads();   // all Afp reads complete (h' overlay may now alias)

    if (mode == 0) {
        if (valid) {
            float s = 0.f;
#pragma unroll
            for (int i = 0; i < 32; ++i) s += v[i];
            s += __shfl_xor(s, 1, 64);
            s += __shfl_xor(s, 2, 64);
            const float mu = s * (1.f / 128.f);
            float vs = 0.f;
#pragma unroll
            for (int i = 0; i < 32; ++i) { const float d = v[i] - mu; vs += d * d; }
            vs += __shfl_xor(vs, 1, 64);
            vs += __shfl_xor(vs, 2, 64);
            const float inv = rsqrtf(vs * (1.f / 128.f) + 1e-5f);
#pragma unroll
            for (int i = 0; i < 8; ++i) {
                const float4 gv = *(const float4*)&g[c0 + i * 4];
                const float4 bv = *(const float4*)&bln[c0 + i * 4];
                unsigned short o[4] = {
                    f2bf((v[i * 4 + 0] - mu) * inv * gv.x + bv.x),
                    f2bf((v[i * 4 + 1] - mu) * inv * gv.y + bv.y),
                    f2bf((v[i * 4 + 2] - mu) * inv * gv.z + bv.z),
                    f2bf((v[i * 4 + 3] - mu) * inv * gv.w + bv.w)
                };
                *(uint2*)&hbf[(size_t)nn * H + c0 + i * 4] = *(const uint2*)o;
                *(uint2*)&A16[rrow * AHS + c0 + i * 4] = *(const uint2*)o;
            }
        }
        __syncthreads();   // h' overlay ready

        // ---- fused premul of NEXT layer: Pa/Pb = f16(h' @ W1n[a|b]) permuted
        {
            s16x8 wf0[4], wf1[4];
#pragma unroll
            for (int kt = 0; kt < 4; ++kt) {
                wf0[kt] = *(const s16x8*)&W1n[(size_t)(colbase + l15) * K1P + kt * 32 + l4 * 8];
                wf1[kt] = *(const s16x8*)&W1n[(size_t)(colbase + 16 + l15) * K1P + kt * 32 + l4 * 8];
            }
            f32x4 pacc[4][2];
#pragma unroll
            for (int mt = 0; mt < 4; ++mt) { pacc[mt][0] = (f32x4)0.f; pacc[mt][1] = (f32x4)0.f; }
#pragma unroll
            for (int kt = 0; kt < 4; ++kt)
#pragma unroll
                for (int mt = 0; mt < 4; ++mt) {
                    const s16x8 a = *(const s16x8*)&A16[(mt * 16 + l15) * AHS + kt * 32 + l4 * 8];
                    pacc[mt][0] = __builtin_amdgcn_mfma_f32_16x16x32_bf16(a, wf0[kt], pacc[mt][0], 0, 0, 0);
                    pacc[mt][1] = __builtin_amdgcn_mfma_f32_16x16x32_bf16(a, wf1[kt], pacc[mt][1], 0, 0, 0);
                }
#pragma unroll
            for (int mt = 0; mt < 4; ++mt)
#pragma unroll
                for (int r = 0; r < 4; ++r) {
                    const int row = mt * 16 + l4 * 4 + r;
                    const int n = n0 + row;
                    if (n < N_NODES)
                        *(unsigned*)&Pa[(size_t)n * H + colbase + 2 * l15] = pk2(pacc[mt][0][r], pacc[mt][1][r]);
                }
        }
        {
            s16x8 wf0[4], wf1[4];
#pragma unroll
            for (int kt = 0; kt < 4; ++kt) {
                wf0[kt] = *(const s16x8*)&W1n[(size_t)(colbase + l15) * K1P + 128 + kt * 32 + l4 * 8];
                wf1[kt] = *(const s16x8*)&W1n[(size_t)(colbase + 16 + l15) * K1P + 128 + kt * 32 + l4 * 8];
            }
            f32x4 pacc[4][2];
#pragma unroll
            for (int mt = 0; mt < 4; ++mt) { pacc[mt][0] = (f32x4)0.f; pacc[mt][1] = (f32x4)0.f; }
#pragma unroll
            for (int kt = 0; kt < 4; ++kt)
#pragma unroll
                for (int mt = 0; mt < 4; ++mt) {
                    const s16x8 a = *(const s16x8*)&A16[(mt * 16 + l15) * AHS + kt * 32 + l4 * 8];
                    pacc[mt][0] = __builtin_amdgcn_mfma_f32_16x16x32_bf16(a, wf0[kt], pacc[mt][0], 0, 0, 0);
                    pacc[mt][1] = __builtin_amdgcn_mfma_f32_16x16x32_bf16(a, wf1[kt], pacc[mt][1], 0, 0, 0);
                }
#pragma unroll
            for (int mt = 0; mt < 4; ++mt)
#pragma unroll
                for (int r = 0; r < 4; ++r) {
                    const int row = mt * 16 + l4 * 4 + r;
                    const int n = n0 + row;
                    if (n < N_NODES)
                        *(unsigned*)&Pb[(size_t)n * H + colbase + 2 * l15] = pk2(pacc[mt][0][r], pacc[mt][1][r]);
                }
        }
    } else {
        if (valid) {
            float s = 0.f;
#pragma unroll
            for (int i = 0; i < 32; ++i) s += v[i];
            s += __shfl_xor(s, 1, 64);
            s += __shfl_xor(s, 2, 64);
            const float mu = s * (1.f / 128.f);
            float vs = 0.f;
#pragma unroll
            for (int i = 0; i < 32; ++i) { const float d = v[i] - mu; vs += d * d; }
            vs += __shfl_xor(vs, 1, 64);
            vs += __shfl_xor(vs, 2, 64);
            const float inv = rsqrtf(vs * (1.f / 128.f) + 1e-5f);
            // ln1 in f32, then LN2(out_g,out_b); stash ln2 in Afp (own slots)
            float h1[32];
            float s2 = 0.f;
#pragma unroll
            for (int i = 0; i < 8; ++i) {
                const float4 gv = *(const float4*)&g[c0 + i * 4];
                const float4 bv = *(const float4*)&bln[c0 + i * 4];
                h1[i * 4 + 0] = (v[i * 4 + 0] - mu) * inv * gv.x + bv.x;
                h1[i * 4 + 1] = (v[i * 4 + 1] - mu) * inv * gv.y + bv.y;
                h1[i * 4 + 2] = (v[i * 4 + 2] - mu) * inv * gv.z + bv.z;
                h1[i * 4 + 3] = (v[i * 4 + 3] - mu) * inv * gv.w + bv.w;
                s2 += h1[i * 4 + 0] + h1[i * 4 + 1] + h1[i * 4 + 2] + h1[i * 4 + 3];
            }
            s2 += __shfl_xor(s2, 1, 64);
            s2 += __shfl_xor(s2, 2, 64);
            const float mu2 = s2 * (1.f / 128.f);
            float vs2 = 0.f;
#pragma unroll
            for (int i = 0; i < 32; ++i) { const float d = h1[i] - mu2; vs2 += d * d; }
            vs2 += __shfl_xor(vs2, 1, 64);
            vs2 += __shfl_xor(vs2, 2, 64);
            const float inv2 = rsqrtf(vs2 * (1.f / 128.f) + 1e-5f);
#pragma unroll
            for (int i = 0; i < 8; ++i) {
                const float4 gv = *(const float4*)&og[c0 + i * 4];
                const float4 bv = *(const float4*)&ob[c0 + i * 4];
                float4 o;
                o.x = (h1[i * 4 + 0] - mu2) * inv2 * gv.x + bv.x;
                o.y = (h1[i * 4 + 1] - mu2) * inv2 * gv.y + bv.y;
                o.z = (h1[i * 4 + 2] - mu2) * inv2 * gv.z + bv.z;
                o.w = (h1[i * 4 + 3] - mu2) * inv2 * gv.w + bv.w;
                *(float4*)&Afp[rrow * FPS + c0 + i * 4] = o;
            }
        } else {
            const float4 z = {0.f, 0.f, 0.f, 0.f};
#pragma unroll
            for (int i = 0; i < 8; ++i)
                *(float4*)&Afp[rrow * FPS + c0 + i * 4] = z;
        }
        __syncthreads();

        // ---- column partial sums of ln2 over the block's 64 rows
        const int col  = tid & 127;
        const int half = tid >> 7;
        float s = 0.f;
        for (int r = half * 32; r < half * 32 + 32; ++r)
            s += Afp[r * FPS + col];
        if (half) csum[col] = s;
        __syncthreads();
        if (!half)
            gpart[(size_t)col * GPR + blockIdx.x] = s + csum[col];
    }
}

// ---------------------------------------------------------------------------
// final_reduce: out[c] = sum_b gpart[c][b] / N  (128 blocks, one per column)
// ---------------------------------------------------------------------------
__global__ __launch_bounds__(256)
void final_reduce(const float* __restrict__ gpart, float* __restrict__ out)
{
    __shared__ float red[4];
    const int c = blockIdx.x;
    const int t = threadIdx.x;
    const int wave = t >> 6, lane = t & 63;
    float s = 0.f;
    for (int r = t; r < UBLK; r += 256) s += gpart[(size_t)c * GPR + r];
#pragma unroll
    for (int off = 32; off > 0; off >>= 1) s += __shfl_xor(s, off, 64);
    if (lane == 0) red[wave] = s;
    __syncthreads();
    if (t == 0) out[c] = (red[0] + red[1] + red[2] + red[3]) * (1.f / N_NODES);
}

// ---------------------------------------------------------------------------
extern "C" void kernel_launch(void* const* d_in, const int* in_sizes, int n_in,
                              void* d_out, int out_size, void* d_ws, size_t ws_size,
                              hipStream_t stream)
{
    const float* x         = (const float*)d_in[0];
    const float* edge_attr = (const float*)d_in[1];
    const int*   edge_idx  = (const int*)  d_in[2];
    const float* proj_W    = (const float*)d_in[3];
    const float* proj_b    = (const float*)d_in[4];
    const float* msg_W1    = (const float*)d_in[5];
    const float* msg_b1    = (const float*)d_in[6];
    const float* msg_W2    = (const float*)d_in[7];
    const float* msg_b2    = (const float*)d_in[8];
    const float* upd_W     = (const float*)d_in[9];
    const float* upd_b     = (const float*)d_in[10];
    const float* ln_g      = (const float*)d_in[11];
    const float* ln_b      = (const float*)d_in[12];
    const float* out_g     = (const float*)d_in[13];
    const float* out_b     = (const float*)d_in[14];
    float* out = (float*)d_out;

    char* w = (char*)d_ws;
    float* agg = (float*)w;                   w += (size_t)N_NODES * H * 4;
    unsigned short* hbf  = (unsigned short*)w; w += (size_t)N_NODES * H * 2;
    unsigned short* Pa   = (unsigned short*)w; w += (size_t)N_NODES * H * 2;
    unsigned short* Pb   = (unsigned short*)w; w += (size_t)N_NODES * H * 2;
    unsigned short* eabf = (unsigned short*)w; w += (size_t)N_EDGES * E_DIM * 2;
    unsigned short* W1t  = (unsigned short*)w; w += (size_t)NLAYERS * H * K1P * 2;
    unsigned short* W2t  = (unsigned short*)w; w += (size_t)NLAYERS * H * H * 2;
    unsigned short* Wut  = (unsigned short*)w; w += (size_t)NLAYERS * H * 256 * 2;
    unsigned short* Wpt  = (unsigned short*)w; w += (size_t)H * DIM_IN * 2;
    float* gpart = (float*)w;                 w += (size_t)H * GPR * 4;
    int* hist   = (int*)w;                    w += (size_t)N_NODES * 4;
    int* cursor = (int*)w;                    w += (size_t)N_NODES * 4;
    int* bsum   = (int*)w;                    w += (size_t)256 * 4;
    int* boff   = (int*)w;                    w += (size_t)256 * 4;
    int* i_s    = (int*)w;                    w += (size_t)N_EDGES * 4;
    int* j_s    = (int*)w;                    w += (size_t)N_EDGES * 4;

    convert_all<<<(NCONV + 255) / 256, 256, 0, stream>>>(
        msg_W1, msg_W2, upd_W, proj_W, W1t, W2t, Wut, Wpt, hist);

    hipMemsetAsync(agg, 0, (size_t)N_NODES * H * sizeof(float), stream);  // once; update re-zeroes
    hist_kernel<<<(N_EDGES + 255) / 256, 256, 0, stream>>>(edge_idx, hist);
    blocksum_kernel<<<NSB, 256, 0, stream>>>(hist, bsum);
    scan_bsum_kernel<<<1, 256, 0, stream>>>(bsum, boff);
    scan_final_kernel<<<NSB, 256, 0, stream>>>(hist, boff, cursor);
    scatter_kernel<<<(N_EDGES + 255) / 256, 256, 0, stream>>>(edge_idx, cursor, edge_attr, i_s, j_s, eabf);

    const int nblk = (N_NODES + MB - 1) / MB;
    proj_mfma<<<nblk, 256, 0, stream>>>(x, Wpt, proj_b, W1t, hbf, Pa, Pb);

    for (int l = 0; l < NLAYERS; ++l) {
        edge_kernel<<<1024, 256, 0, stream>>>(
            Pa, Pb, eabf, i_s, j_s,
            W1t + (size_t)l * H * K1P, msg_b1 + (size_t)l * H,
            W2t + (size_t)l * H * H,   msg_b2 + (size_t)l * H, agg);
        update_mfma<<<UBLK, 256, 0, stream>>>(
            hbf, agg, Wut + (size_t)l * H * 256, upd_b + (size_t)l * H,
            ln_g + (size_t)l * H, ln_b + (size_t)l * H,
            W1t + (size_t)((l < NLAYERS - 1) ? (l + 1) : 0) * H * K1P,
            Pa, Pb, out_g, out_b, gpart,
            (l < NLAYERS - 1) ? 0 : 1);
    }

    final_reduce<<<H, 256, 0, stream>>>(gpart, out);
}